// Round 1
// baseline (370.929 us; speedup 1.0000x reference)
//
#include <hip/hip_runtime.h>

typedef __bf16 bf16;
typedef __bf16 bf16x8 __attribute__((ext_vector_type(8)));
typedef float f32x4 __attribute__((ext_vector_type(4)));

#define DEPTH   18
#define N_NODES ((1 << DEPTH) - 1)      // 262143
#define LEAF_N  (1 << (DEPTH - 1))      // 131072
#define KDIM    192                     // E + 2H
#define RDIM    320                     // 3H + 2H
#define LDS_PAD 200                     // padded row stride (elements)

__device__ __forceinline__ float sigf(float x) { return 1.f / (1.f + __expf(-x)); }
__device__ __forceinline__ float tanhf_(float x) { float s = sigf(2.f * x); return 2.f * s - 1.f; }

// ---- one-time: pack [W_iou|U_iou ; W_f|U_f] -> bf16 Wcat[320][192], bias[320] ----
__global__ void prep_weights(const float* __restrict__ W_iou, const float* __restrict__ U_iou,
                             const float* __restrict__ W_f,   const float* __restrict__ U_f,
                             const float* __restrict__ b_Wiou, const float* __restrict__ b_Uiou,
                             const float* __restrict__ b_Wf,   const float* __restrict__ b_Uf,
                             bf16* __restrict__ Wcat, float* __restrict__ bias) {
    int t = blockIdx.x * blockDim.x + threadIdx.x;
    if (t < RDIM * KDIM) {
        int r = t / KDIM, k = t % KDIM;
        float v;
        if (r < 192) v = (k < 64) ? W_iou[r * 64 + k] : U_iou[r * 128 + (k - 64)];
        else { int rr = r - 192; v = (k < 64) ? W_f[rr * 64 + k] : U_f[rr * 128 + (k - 64)]; }
        Wcat[t] = (bf16)v;
    }
    if (t < RDIM) {
        bias[t] = (t < 192) ? (b_Wiou[t] + b_Uiou[t]) : (b_Wf[t - 192] + b_Uf[t - 192]);
    }
}

// ---- one-time: In[node][0:64] = bf16(emb[token_ids[node]]) ----
__global__ void gather_x(const int* __restrict__ token_ids, const float* __restrict__ emb,
                         bf16* __restrict__ In) {
    int t = blockIdx.x * blockDim.x + threadIdx.x;   // N_NODES*16 threads, 4 elems each
    if (t >= N_NODES * 16) return;
    int node = t >> 4, k4 = (t & 15) << 2;
    int tok = token_ids[node];
    float4 v = *(const float4*)(emb + tok * 64 + k4);
    union { bf16 b[4]; uint2 u; } p;
    p.b[0] = (bf16)v.x; p.b[1] = (bf16)v.y; p.b[2] = (bf16)v.z; p.b[3] = (bf16)v.w;
    *(uint2*)(In + (size_t)node * KDIM + k4) = p.u;
}

// ---- one-time: zero h-slots of leaf rows (h_cat = 0 at leaves) ----
__global__ void zero_leaf(bf16* __restrict__ In) {
    int t = blockIdx.x * blockDim.x + threadIdx.x;   // LEAF_N*16 threads, 8 bf16 (16B) each
    if (t >= LEAF_N * 16) return;
    int node = (LEAF_N - 1) + (t >> 4);
    int off = 64 + ((t & 15) << 3);
    *(uint4*)(In + (size_t)node * KDIM + off) = make_uint4(0u, 0u, 0u, 0u);
}

// ---- per-level fused GEMM + gates ----
// Block: 256 threads (4 waves), 32 nodes. Wave w owns out-cols j in [16w,16w+16)
// for all 5 gates (tiles {w,4+w,8+w,12+w,16+w}) -> gate math fully in-register.
__global__ __launch_bounds__(256) void level_pass(
        const bf16* __restrict__ Wcat, const float* __restrict__ bias,
        bf16* __restrict__ In, float* __restrict__ c_buf, float* __restrict__ out,
        int level_start, int n, int flags /*1=leaf, 2=root*/) {
    __shared__ bf16 Alds[32 * LDS_PAD];
    const int tid = threadIdx.x;
    const int node0 = blockIdx.x * 32;

    // stage 32 In rows -> LDS (rows beyond n read valid deeper-level data; discarded later)
    {
        const bf16* src = In + (size_t)(level_start + node0) * KDIM;
        for (int c = tid; c < 32 * 24; c += 256) {    // 24 x 16B chunks per row
            int nrow = c / 24, c16 = c % 24;
            uint4 v = *(const uint4*)(src + nrow * KDIM + c16 * 8);
            *(uint4*)(&Alds[nrow * LDS_PAD + c16 * 8]) = v;
        }
    }
    __syncthreads();

    const int wave = tid >> 6, lane = tid & 63;
    const int l15 = lane & 15, quad = lane >> 4;

    f32x4 acc[2][5];
#pragma unroll
    for (int t = 0; t < 2; t++)
#pragma unroll
        for (int g = 0; g < 5; g++) acc[t][g] = (f32x4){0.f, 0.f, 0.f, 0.f};

#pragma unroll
    for (int kb = 0; kb < 6; kb++) {
        bf16x8 a[2], b[5];
#pragma unroll
        for (int t = 0; t < 2; t++)
            a[t] = *(const bf16x8*)(&Alds[(t * 16 + l15) * LDS_PAD + kb * 32 + quad * 8]);
#pragma unroll
        for (int g = 0; g < 5; g++) {
            int r = g * 64 + wave * 16 + l15;
            b[g] = *(const bf16x8*)(Wcat + r * KDIM + kb * 32 + quad * 8);
        }
#pragma unroll
        for (int t = 0; t < 2; t++)
#pragma unroll
            for (int g = 0; g < 5; g++)
                acc[t][g] = __builtin_amdgcn_mfma_f32_16x16x32_bf16(a[t], b[g], acc[t][g], 0, 0, 0);
    }

    // epilogue: gates + cell update + scatter h into parent's In row
    const int j = wave * 16 + l15;
    const float bi  = bias[j],        bo  = bias[64 + j],  bu = bias[128 + j];
    const float bfl = bias[192 + j],  bfr = bias[256 + j];
    const bool leaf = (flags & 1), root = (flags & 2);

#pragma unroll
    for (int t = 0; t < 2; t++) {
#pragma unroll
        for (int r = 0; r < 4; r++) {
            int nrow = t * 16 + quad * 4 + r;     // == MFMA D row
            int node = node0 + nrow;
            if (node >= n) continue;
            int gn = level_start + node;
            float i_g = sigf(acc[t][0][r] + bi);
            float o_g = sigf(acc[t][1][r] + bo);
            float u_g = tanhf_(sigf(acc[t][2][r] + bu));   // ref: tanh(sigmoid(pre_u))
            float fl  = sigf(acc[t][3][r] + bfl);
            float fr  = sigf(acc[t][4][r] + bfr);
            float cl = 0.f, cr = 0.f;
            if (!leaf) {
                cl = c_buf[(size_t)(2 * gn + 1) * 64 + j];
                cr = c_buf[(size_t)(2 * gn + 2) * 64 + j];
            }
            float c = i_g * u_g + fl * cl + fr * cr;
            float h = o_g * tanhf_(c);
            c_buf[(size_t)gn * 64 + j] = c;
            if (root) {
                out[j] = h; out[64 + j] = c;      // stack([h, c])
            } else {
                int parent = (gn - 1) >> 1;
                int slot = (gn & 1) ? 64 : 128;   // odd = left child, even = right child
                In[(size_t)parent * KDIM + slot + j] = (bf16)h;
            }
        }
    }
}

extern "C" void kernel_launch(void* const* d_in, const int* in_sizes, int n_in,
                              void* d_out, int out_size, void* d_ws, size_t ws_size,
                              hipStream_t stream) {
    const int*   token_ids = (const int*)d_in[0];
    const float* emb       = (const float*)d_in[1];
    const float* W_iou     = (const float*)d_in[2];
    const float* b_Wiou    = (const float*)d_in[3];
    const float* U_iou     = (const float*)d_in[4];
    const float* b_Uiou    = (const float*)d_in[5];
    const float* W_f       = (const float*)d_in[6];
    const float* b_Wf      = (const float*)d_in[7];
    const float* U_f       = (const float*)d_in[8];
    const float* b_Uf      = (const float*)d_in[9];
    // d_in[10] = depth (compile-time 18)
    float* out = (float*)d_out;

    char* ws = (char*)d_ws;
    bf16*  Wcat  = (bf16*)ws;                                  // 320*192*2   = 122880 B
    float* bias  = (float*)(ws + 122880);                      // 320*4       = 1280 B
    bf16*  In    = (bf16*)(ws + 124160);                       // N*192*2     = 100,662,912 B
    float* c_buf = (float*)(ws + 124160 + (size_t)N_NODES * KDIM * 2);  // N*64*4 = 67,108,608 B

    prep_weights<<<(RDIM * KDIM + 255) / 256, 256, 0, stream>>>(
        W_iou, U_iou, W_f, U_f, b_Wiou, b_Uiou, b_Wf, b_Uf, Wcat, bias);
    gather_x<<<(N_NODES * 16 + 255) / 256, 256, 0, stream>>>(token_ids, emb, In);
    zero_leaf<<<(LEAF_N * 16 + 255) / 256, 256, 0, stream>>>(In);

    for (int l = DEPTH - 1; l >= 0; l--) {
        int n = 1 << l;
        int s = n - 1;
        int flags = (l == DEPTH - 1 ? 1 : 0) | (l == 0 ? 2 : 0);
        level_pass<<<(n + 31) / 32, 256, 0, stream>>>(Wcat, bias, In, c_buf, out, s, n, flags);
    }
}

// Round 2
// 332.953 us; speedup vs baseline: 1.1141x; 1.1141x over previous
//
#include <hip/hip_runtime.h>

typedef __bf16 bf16;
typedef __bf16 bf16x8 __attribute__((ext_vector_type(8)));
typedef float f32x4 __attribute__((ext_vector_type(4)));

#define DEPTH   18
#define N_NODES ((1 << DEPTH) - 1)      // 262143
#define KDIM    192                     // E + 2H
#define RDIM    320                     // 3H + 2H
#define LDS_PAD 200                     // padded A-row stride (bf16 elems)
#define NPB     64                      // nodes per block (big levels)
#define LOG2E   1.4426950408889634f

__device__ __forceinline__ float rcpf(float x) { return __builtin_amdgcn_rcpf(x); }
// pre-activations are pre-scaled by log2e (folded into Wcat/bias)
__device__ __forceinline__ float sig2(float p)  { return rcpf(1.f + exp2f(-p)); }
__device__ __forceinline__ float tanhf_(float x){ return 2.f * rcpf(1.f + exp2f(-2.f * LOG2E * x)) - 1.f; }

// ---- one-time: Wcat[320][192]*log2e -> bf16, bias*log2e, emb -> bf16 ----
__global__ void prep(const float* __restrict__ emb,
                     const float* __restrict__ W_iou, const float* __restrict__ U_iou,
                     const float* __restrict__ W_f,   const float* __restrict__ U_f,
                     const float* __restrict__ b_Wiou, const float* __restrict__ b_Uiou,
                     const float* __restrict__ b_Wf,   const float* __restrict__ b_Uf,
                     bf16* __restrict__ Wcat, float* __restrict__ bias, bf16* __restrict__ emb16) {
    int t = blockIdx.x * blockDim.x + threadIdx.x;
    if (t < 2048 * 64) emb16[t] = (bf16)emb[t];
    if (t < RDIM * KDIM) {
        int r = t / KDIM, k = t % KDIM;
        float v;
        if (r < 192) v = (k < 64) ? W_iou[r * 64 + k] : U_iou[r * 128 + (k - 64)];
        else { int rr = r - 192; v = (k < 64) ? W_f[rr * 64 + k] : U_f[rr * 128 + (k - 64)]; }
        Wcat[t] = (bf16)(v * LOG2E);
    }
    if (t < RDIM)
        bias[t] = ((t < 192) ? (b_Wiou[t] + b_Uiou[t]) : (b_Wf[t - 192] + b_Uf[t - 192])) * LOG2E;
}

// ---- big levels (l >= 8): 64 nodes/block, 4 waves; wave w owns out-cols 16w..16w+15
// for all 5 gates; children h read as contiguous 256B from H; h stored coalesced. ----
__global__ __launch_bounds__(256) void level_pass(
        const bf16* __restrict__ Wcat, const float* __restrict__ bias,
        const bf16* __restrict__ emb16, const int* __restrict__ token_ids,
        bf16* __restrict__ H, float* __restrict__ c_buf,
        int level_start, int n, int leaf) {
    __shared__ __align__(16) bf16 A[NPB * LDS_PAD];
    const int tid = threadIdx.x;
    const int node0 = blockIdx.x * NPB;

    // stage x = emb16[token]  (64 rows x 8 chunks of 16B)
    for (int ch = tid; ch < NPB * 8; ch += 256) {
        int nrow = ch >> 3, k8 = (ch & 7) << 3;
        int tok = token_ids[level_start + node0 + nrow];
        *(uint4*)&A[nrow * LDS_PAD + k8] = *(const uint4*)(emb16 + tok * 64 + k8);
    }
    // stage h_cat = [h(2gn+1) | h(2gn+2)] contiguous in H  (64 rows x 16 chunks)
    if (leaf) {
        const uint4 z = make_uint4(0u, 0u, 0u, 0u);
        for (int ch = tid; ch < NPB * 16; ch += 256) {
            int nrow = ch >> 4, k8 = (ch & 15) << 3;
            *(uint4*)&A[nrow * LDS_PAD + 64 + k8] = z;
        }
    } else {
        for (int ch = tid; ch < NPB * 16; ch += 256) {
            int nrow = ch >> 4, k8 = (ch & 15) << 3;
            int gn = level_start + node0 + nrow;
            *(uint4*)&A[nrow * LDS_PAD + 64 + k8] =
                *(const uint4*)(H + (size_t)(2 * gn + 1) * 64 + k8);
        }
    }
    __syncthreads();

    const int wave = tid >> 6, lane = tid & 63;
    const int l15 = lane & 15, quad = lane >> 4;
    const int j = wave * 16 + l15;

    f32x4 acc[4][5];
#pragma unroll
    for (int t = 0; t < 4; t++)
#pragma unroll
        for (int g = 0; g < 5; g++) acc[t][g] = (f32x4){0.f, 0.f, 0.f, 0.f};

#pragma unroll
    for (int kb = 0; kb < 6; kb++) {
        bf16x8 a[4], b[5];
#pragma unroll
        for (int t = 0; t < 4; t++)
            a[t] = *(const bf16x8*)(&A[(t * 16 + l15) * LDS_PAD + kb * 32 + quad * 8]);
#pragma unroll
        for (int g = 0; g < 5; g++)
            b[g] = *(const bf16x8*)(Wcat + (g * 64 + j) * KDIM + kb * 32 + quad * 8);
#pragma unroll
        for (int t = 0; t < 4; t++)
#pragma unroll
            for (int g = 0; g < 5; g++)
                acc[t][g] = __builtin_amdgcn_mfma_f32_16x16x32_bf16(a[t], b[g], acc[t][g], 0, 0, 0);
    }

    const float bi  = bias[j],       bo  = bias[64 + j], bu = bias[128 + j];
    const float bfl = bias[192 + j], bfr = bias[256 + j];

#pragma unroll
    for (int t = 0; t < 4; t++) {
#pragma unroll
        for (int r = 0; r < 4; r++) {
            int nrow = t * 16 + quad * 4 + r;          // MFMA D row
            int gn = level_start + node0 + nrow;       // node0+nrow < n guaranteed (n % 64 == 0)
            float i_g = sig2(acc[t][0][r] + bi);
            float o_g = sig2(acc[t][1][r] + bo);
            float u_g = tanhf_(sig2(acc[t][2][r] + bu));   // ref: tanh(sigmoid(pre_u))
            float fl  = sig2(acc[t][3][r] + bfl);
            float fr  = sig2(acc[t][4][r] + bfr);
            float cl = 0.f, cr = 0.f;
            if (!leaf) {
                cl = c_buf[(size_t)(2 * gn + 1) * 64 + j];
                cr = c_buf[(size_t)(2 * gn + 2) * 64 + j];
            }
            float c = i_g * u_g + fl * cl + fr * cr;
            float h = o_g * tanhf_(c);
            c_buf[(size_t)gn * 64 + j] = c;
            H[(size_t)gn * 64 + j] = (bf16)h;
        }
    }
}

// ---- tail: levels 7..0 (255 nodes) in ONE block; h ping-pong in LDS (paired
// layout, stride 136 to dodge bank conflicts), c through global (L2) + fence. ----
__global__ __launch_bounds__(256) void tail_pass(
        const bf16* __restrict__ Wcat, const float* __restrict__ bias,
        const bf16* __restrict__ emb16, const int* __restrict__ token_ids,
        const bf16* __restrict__ H, float* c_buf, float* out) {
    __shared__ __align__(16) bf16 buf0[128 * 136];   // pair p = [h(left)|h(right)], 128 elems + pad
    __shared__ __align__(16) bf16 buf1[64 * 136];
    const int tid = threadIdx.x;

    // preload level-8 h (nodes 255..510 = 128 pairs) into buf0
    for (int ch = tid; ch < 128 * 16; ch += 256) {
        int pair = ch >> 4, k8 = (ch & 15) << 3;
        *(uint4*)&buf0[pair * 136 + k8] = *(const uint4*)(H + (size_t)(255 + 2 * pair) * 64 + k8);
    }
    __syncthreads();

    const int wave = tid >> 6, lane = tid & 63;
    const int l15 = lane & 15, quad = lane >> 4;
    const int j = wave * 16 + l15;
    const float bi  = bias[j],       bo  = bias[64 + j], bu = bias[128 + j];
    const float bfl = bias[192 + j], bfr = bias[256 + j];

    bf16* prev = buf0;
    bf16* cur  = buf1;

    for (int l = 7; l >= 0; l--) {
        const int n = 1 << l, start = n - 1;
        for (int c0 = 0; c0 < n; c0 += 64) {
            f32x4 acc[4][5];
#pragma unroll
            for (int t = 0; t < 4; t++)
#pragma unroll
                for (int g = 0; g < 5; g++) acc[t][g] = (f32x4){0.f, 0.f, 0.f, 0.f};

            int toks[4], idxc[4];
#pragma unroll
            for (int t = 0; t < 4; t++) {
                int idx = c0 + t * 16 + l15;
                idxc[t] = (idx < n) ? idx : (n - 1);      // clamp for LDS reads
                toks[t] = token_ids[start + idx];          // deeper-tree tokens OK (discarded)
            }
#pragma unroll
            for (int kb = 0; kb < 6; kb++) {
                bf16x8 a[4], b[5];
#pragma unroll
                for (int t = 0; t < 4; t++) {
                    if (kb < 2)
                        a[t] = *(const bf16x8*)(emb16 + toks[t] * 64 + kb * 32 + quad * 8);
                    else
                        a[t] = *(const bf16x8*)(prev + idxc[t] * 136 + (kb * 32 + quad * 8 - 64));
                }
#pragma unroll
                for (int g = 0; g < 5; g++)
                    b[g] = *(const bf16x8*)(Wcat + (g * 64 + j) * KDIM + kb * 32 + quad * 8);
#pragma unroll
                for (int t = 0; t < 4; t++)
#pragma unroll
                    for (int g = 0; g < 5; g++)
                        acc[t][g] = __builtin_amdgcn_mfma_f32_16x16x32_bf16(a[t], b[g], acc[t][g], 0, 0, 0);
            }
#pragma unroll
            for (int t = 0; t < 4; t++) {
#pragma unroll
                for (int r = 0; r < 4; r++) {
                    int idx = c0 + t * 16 + quad * 4 + r;
                    if (idx >= n) continue;
                    int gn = start + idx;
                    float i_g = sig2(acc[t][0][r] + bi);
                    float o_g = sig2(acc[t][1][r] + bo);
                    float u_g = tanhf_(sig2(acc[t][2][r] + bu));
                    float fl  = sig2(acc[t][3][r] + bfl);
                    float fr  = sig2(acc[t][4][r] + bfr);
                    float cl = c_buf[(size_t)(2 * gn + 1) * 64 + j];
                    float cr = c_buf[(size_t)(2 * gn + 2) * 64 + j];
                    float c = i_g * u_g + fl * cl + fr * cr;
                    float h = o_g * tanhf_(c);
                    c_buf[(size_t)gn * 64 + j] = c;
                    if (l) cur[(idx >> 1) * 136 + (idx & 1) * 64 + j] = (bf16)h;
                    else { out[j] = h; out[64 + j] = c; }   // stack([h, c])
                }
            }
        }
        __threadfence();      // make c_buf writes visible (and invalidate L1) for next level
        __syncthreads();
        bf16* tmp = prev; prev = cur; cur = tmp;
    }
}

extern "C" void kernel_launch(void* const* d_in, const int* in_sizes, int n_in,
                              void* d_out, int out_size, void* d_ws, size_t ws_size,
                              hipStream_t stream) {
    const int*   token_ids = (const int*)d_in[0];
    const float* emb       = (const float*)d_in[1];
    const float* W_iou     = (const float*)d_in[2];
    const float* b_Wiou    = (const float*)d_in[3];
    const float* U_iou     = (const float*)d_in[4];
    const float* b_Uiou    = (const float*)d_in[5];
    const float* W_f       = (const float*)d_in[6];
    const float* b_Wf      = (const float*)d_in[7];
    const float* U_f       = (const float*)d_in[8];
    const float* b_Uf      = (const float*)d_in[9];
    float* out = (float*)d_out;

    char* ws = (char*)d_ws;
    bf16*  Wcat  = (bf16*)ws;                               // 122880 B
    float* bias  = (float*)(ws + 122880);                   // 1280 B
    bf16*  emb16 = (bf16*)(ws + 124160);                    // 262144 B
    bf16*  H     = (bf16*)(ws + 386304);                    // N*64*2 = 33,554,304 B
    float* c_buf = (float*)(ws + 386304 + (size_t)N_NODES * 64 * 2);  // N*64*4 B

    prep<<<512, 256, 0, stream>>>(emb, W_iou, U_iou, W_f, U_f,
                                  b_Wiou, b_Uiou, b_Wf, b_Uf, Wcat, bias, emb16);

    for (int l = DEPTH - 1; l >= 8; l--) {
        int n = 1 << l;
        level_pass<<<n / NPB, 256, 0, stream>>>(Wcat, bias, emb16, token_ids,
                                                H, c_buf, n - 1, n, l == DEPTH - 1);
    }
    tail_pass<<<1, 256, 0, stream>>>(Wcat, bias, emb16, token_ids, H, c_buf, out);
}

// Round 3
// 287.469 us; speedup vs baseline: 1.2903x; 1.1582x over previous
//
#include <hip/hip_runtime.h>

typedef __bf16 bf16;
typedef __bf16 bf16x8 __attribute__((ext_vector_type(8)));
typedef float f32x4 __attribute__((ext_vector_type(4)));

#define DEPTH   18
#define N_NODES ((1 << DEPTH) - 1)      // 262143
#define KDIM    192                     // E + 2H
#define RDIM    320                     // 3H + 2H
#define LDS_PAD 200                     // padded A-row stride (bf16 elems)
#define NPB     64                      // nodes per block (big levels)
#define LOG2E   1.4426950408889634f

__device__ __forceinline__ float rcpf(float x) { return __builtin_amdgcn_rcpf(x); }
// pre-activations are pre-scaled by log2e (folded into Wcat/bias)
__device__ __forceinline__ float sig2(float p)  { return rcpf(1.f + exp2f(-p)); }
__device__ __forceinline__ float tanhf_(float x){ return 2.f * rcpf(1.f + exp2f(-2.f * LOG2E * x)) - 1.f; }

// ---- one-time: Wcat[320][192]*log2e -> bf16, bias*log2e, emb -> bf16 ----
__global__ void prep(const float* __restrict__ emb,
                     const float* __restrict__ W_iou, const float* __restrict__ U_iou,
                     const float* __restrict__ W_f,   const float* __restrict__ U_f,
                     const float* __restrict__ b_Wiou, const float* __restrict__ b_Uiou,
                     const float* __restrict__ b_Wf,   const float* __restrict__ b_Uf,
                     bf16* __restrict__ Wcat, float* __restrict__ bias, bf16* __restrict__ emb16) {
    int t = blockIdx.x * blockDim.x + threadIdx.x;
    if (t < 2048 * 64) emb16[t] = (bf16)emb[t];
    if (t < RDIM * KDIM) {
        int r = t / KDIM, k = t % KDIM;
        float v;
        if (r < 192) v = (k < 64) ? W_iou[r * 64 + k] : U_iou[r * 128 + (k - 64)];
        else { int rr = r - 192; v = (k < 64) ? W_f[rr * 64 + k] : U_f[rr * 128 + (k - 64)]; }
        Wcat[t] = (bf16)(v * LOG2E);
    }
    if (t < RDIM)
        bias[t] = ((t < 192) ? (b_Wiou[t] + b_Uiou[t]) : (b_Wf[t - 192] + b_Uf[t - 192])) * LOG2E;
}

// ---- big levels (l >= 8): 64 nodes/block, 4 waves.
// OPERAND-SWAPPED MFMA: a = W-fragment, b = node-fragment -> D row = j-sub,
// col = node. Each thread: 1 node x 4 consecutive j per gate -> float4/bf16x4
// epilogue (children-c loads, c store, h store all vectorized). ----
__global__ __launch_bounds__(256) void level_pass(
        const bf16* __restrict__ Wcat, const float* __restrict__ bias,
        const bf16* __restrict__ emb16, const int* __restrict__ token_ids,
        bf16* __restrict__ H, float* __restrict__ c_buf,
        int level_start, int n, int leaf) {
    __shared__ __align__(16) bf16 A[NPB * LDS_PAD];
    const int tid = threadIdx.x;
    const int node0 = blockIdx.x * NPB;

    // stage x = emb16[token]  (64 rows x 8 chunks of 16B)
    for (int ch = tid; ch < NPB * 8; ch += 256) {
        int nrow = ch >> 3, k8 = (ch & 7) << 3;
        int tok = token_ids[level_start + node0 + nrow];
        *(uint4*)&A[nrow * LDS_PAD + k8] = *(const uint4*)(emb16 + tok * 64 + k8);
    }
    // stage h_cat = [h(2gn+1) | h(2gn+2)] contiguous in H  (64 rows x 16 chunks)
    if (leaf) {
        const uint4 z = make_uint4(0u, 0u, 0u, 0u);
        for (int ch = tid; ch < NPB * 16; ch += 256) {
            int nrow = ch >> 4, k8 = (ch & 15) << 3;
            *(uint4*)&A[nrow * LDS_PAD + 64 + k8] = z;
        }
    } else {
        for (int ch = tid; ch < NPB * 16; ch += 256) {
            int nrow = ch >> 4, k8 = (ch & 15) << 3;
            int gn = level_start + node0 + nrow;
            *(uint4*)&A[nrow * LDS_PAD + 64 + k8] =
                *(const uint4*)(H + (size_t)(2 * gn + 1) * 64 + k8);
        }
    }
    __syncthreads();

    const int wave = tid >> 6, lane = tid & 63;
    const int l15 = lane & 15, quad = lane >> 4;
    const int jw = wave * 16;             // wave's j-base
    const int jb = jw + quad * 4;         // this thread's 4-j base

    f32x4 acc[4][5];
#pragma unroll
    for (int t = 0; t < 4; t++)
#pragma unroll
        for (int g = 0; g < 5; g++) acc[t][g] = (f32x4){0.f, 0.f, 0.f, 0.f};

#pragma unroll
    for (int kb = 0; kb < 6; kb++) {
        bf16x8 wfrag[5], nfrag[4];
#pragma unroll
        for (int g = 0; g < 5; g++)
            wfrag[g] = *(const bf16x8*)(Wcat + (g * 64 + jw + l15) * KDIM + kb * 32 + quad * 8);
#pragma unroll
        for (int t = 0; t < 4; t++)
            nfrag[t] = *(const bf16x8*)(&A[(t * 16 + l15) * LDS_PAD + kb * 32 + quad * 8]);
#pragma unroll
        for (int t = 0; t < 4; t++)
#pragma unroll
            for (int g = 0; g < 5; g++)
                acc[t][g] = __builtin_amdgcn_mfma_f32_16x16x32_bf16(wfrag[g], nfrag[t], acc[t][g], 0, 0, 0);
    }

    const float4 bI = *(const float4*)(bias + jb);
    const float4 bO = *(const float4*)(bias + 64 + jb);
    const float4 bU = *(const float4*)(bias + 128 + jb);
    const float4 bL = *(const float4*)(bias + 192 + jb);
    const float4 bR = *(const float4*)(bias + 256 + jb);

#pragma unroll
    for (int t = 0; t < 4; t++) {
        const int node = node0 + t * 16 + l15;
        const int gn = level_start + node;
        float4 cl = make_float4(0.f, 0.f, 0.f, 0.f), cr = cl;
        if (!leaf) {
            cl = *(const float4*)(c_buf + (size_t)(2 * gn + 1) * 64 + jb);
            cr = *(const float4*)(c_buf + (size_t)(2 * gn + 2) * 64 + jb);
        }
        float4 c4;
        union { bf16 h[4]; uint2 u; } hp;
        const float* pbI = &bI.x; const float* pbO = &bO.x; const float* pbU = &bU.x;
        const float* pbL = &bL.x; const float* pbR = &bR.x;
        const float* pcl = &cl.x; const float* pcr = &cr.x;
        float* pc4 = &c4.x;
#pragma unroll
        for (int r = 0; r < 4; r++) {
            float i_g = sig2(acc[t][0][r] + pbI[r]);
            float o_g = sig2(acc[t][1][r] + pbO[r]);
            float u_g = tanhf_(sig2(acc[t][2][r] + pbU[r]));   // ref: tanh(sigmoid(pre_u))
            float fl  = sig2(acc[t][3][r] + pbL[r]);
            float fr  = sig2(acc[t][4][r] + pbR[r]);
            float c = i_g * u_g + fl * pcl[r] + fr * pcr[r];
            pc4[r] = c;
            hp.h[r] = (bf16)(o_g * tanhf_(c));
        }
        *(float4*)(c_buf + (size_t)gn * 64 + jb) = c4;
        *(uint2*)(H + (size_t)gn * 64 + jb) = hp.u;
    }
}

// ---- tail: levels 7..0 (255 nodes) in ONE block; h ping-pong in LDS, c via
// global L2 (same-workgroup visibility: __syncthreads suffices, NO fence). ----
__global__ __launch_bounds__(256) void tail_pass(
        const bf16* __restrict__ Wcat, const float* __restrict__ bias,
        const bf16* __restrict__ emb16, const int* __restrict__ token_ids,
        const bf16* __restrict__ H, float* c_buf, float* out) {
    __shared__ __align__(16) bf16 buf0[128 * 136];   // pair p = [h(left)|h(right)] + pad
    __shared__ __align__(16) bf16 buf1[64 * 136];
    const int tid = threadIdx.x;

    // preload level-8 h (nodes 255..510 = 128 pairs) into buf0
    for (int ch = tid; ch < 128 * 16; ch += 256) {
        int pair = ch >> 4, k8 = (ch & 15) << 3;
        *(uint4*)&buf0[pair * 136 + k8] = *(const uint4*)(H + (size_t)(255 + 2 * pair) * 64 + k8);
    }
    __syncthreads();

    const int wave = tid >> 6, lane = tid & 63;
    const int l15 = lane & 15, quad = lane >> 4;
    const int jw = wave * 16, jb = jw + quad * 4;
    const float4 bI = *(const float4*)(bias + jb);
    const float4 bO = *(const float4*)(bias + 64 + jb);
    const float4 bU = *(const float4*)(bias + 128 + jb);
    const float4 bL = *(const float4*)(bias + 192 + jb);
    const float4 bR = *(const float4*)(bias + 256 + jb);

    bf16* prev = buf0;
    bf16* cur  = buf1;

    for (int l = 7; l >= 0; l--) {
        const int n = 1 << l, start = n - 1;
        for (int c0 = 0; c0 < n; c0 += 64) {
            f32x4 acc[4][5];
#pragma unroll
            for (int t = 0; t < 4; t++)
#pragma unroll
                for (int g = 0; g < 5; g++) acc[t][g] = (f32x4){0.f, 0.f, 0.f, 0.f};

            int toks[4], idxc[4];
#pragma unroll
            for (int t = 0; t < 4; t++) {
                int idx = c0 + t * 16 + l15;
                idxc[t] = (idx < n) ? idx : (n - 1);      // clamp for LDS reads
                toks[t] = token_ids[start + idx];          // deeper-tree tokens OK (discarded)
            }
#pragma unroll
            for (int kb = 0; kb < 6; kb++) {
                bf16x8 wfrag[5], nfrag[4];
#pragma unroll
                for (int g = 0; g < 5; g++)
                    wfrag[g] = *(const bf16x8*)(Wcat + (g * 64 + jw + l15) * KDIM + kb * 32 + quad * 8);
#pragma unroll
                for (int t = 0; t < 4; t++) {
                    if (kb < 2)
                        nfrag[t] = *(const bf16x8*)(emb16 + toks[t] * 64 + kb * 32 + quad * 8);
                    else
                        nfrag[t] = *(const bf16x8*)(prev + idxc[t] * 136 + (kb * 32 + quad * 8 - 64));
                }
#pragma unroll
                for (int t = 0; t < 4; t++)
#pragma unroll
                    for (int g = 0; g < 5; g++)
                        acc[t][g] = __builtin_amdgcn_mfma_f32_16x16x32_bf16(wfrag[g], nfrag[t], acc[t][g], 0, 0, 0);
            }
#pragma unroll
            for (int t = 0; t < 4; t++) {
                const int idx = c0 + t * 16 + l15;
                if (idx >= n) continue;
                const int gn = start + idx;
                float4 cl = *(const float4*)(c_buf + (size_t)(2 * gn + 1) * 64 + jb);
                float4 cr = *(const float4*)(c_buf + (size_t)(2 * gn + 2) * 64 + jb);
                float4 c4, h4;
                union { bf16 h[4]; uint2 u; } hp;
                const float* pbI = &bI.x; const float* pbO = &bO.x; const float* pbU = &bU.x;
                const float* pbL = &bL.x; const float* pbR = &bR.x;
                const float* pcl = &cl.x; const float* pcr = &cr.x;
                float* pc4 = &c4.x; float* ph4 = &h4.x;
#pragma unroll
                for (int r = 0; r < 4; r++) {
                    float i_g = sig2(acc[t][0][r] + pbI[r]);
                    float o_g = sig2(acc[t][1][r] + pbO[r]);
                    float u_g = tanhf_(sig2(acc[t][2][r] + pbU[r]));
                    float fl  = sig2(acc[t][3][r] + pbL[r]);
                    float fr  = sig2(acc[t][4][r] + pbR[r]);
                    float c = i_g * u_g + fl * pcl[r] + fr * pcr[r];
                    pc4[r] = c;
                    float h = o_g * tanhf_(c);
                    ph4[r] = h;
                    hp.h[r] = (bf16)h;
                }
                *(float4*)(c_buf + (size_t)gn * 64 + jb) = c4;
                if (l) {
                    *(uint2*)(cur + (idx >> 1) * 136 + (idx & 1) * 64 + jb) = hp.u;
                } else {
                    *(float4*)(out + jb) = h4;            // stack([h, c]): h
                    *(float4*)(out + 64 + jb) = c4;       // c
                }
            }
        }
        __syncthreads();      // same-CU global c_buf visibility: barrier suffices
        bf16* tmp = prev; prev = cur; cur = tmp;
    }
}

extern "C" void kernel_launch(void* const* d_in, const int* in_sizes, int n_in,
                              void* d_out, int out_size, void* d_ws, size_t ws_size,
                              hipStream_t stream) {
    const int*   token_ids = (const int*)d_in[0];
    const float* emb       = (const float*)d_in[1];
    const float* W_iou     = (const float*)d_in[2];
    const float* b_Wiou    = (const float*)d_in[3];
    const float* U_iou     = (const float*)d_in[4];
    const float* b_Uiou    = (const float*)d_in[5];
    const float* W_f       = (const float*)d_in[6];
    const float* b_Wf      = (const float*)d_in[7];
    const float* U_f       = (const float*)d_in[8];
    const float* b_Uf      = (const float*)d_in[9];
    float* out = (float*)d_out;

    char* ws = (char*)d_ws;
    bf16*  Wcat  = (bf16*)ws;                               // 122880 B
    float* bias  = (float*)(ws + 122880);                   // 1280 B
    bf16*  emb16 = (bf16*)(ws + 124160);                    // 262144 B
    bf16*  H     = (bf16*)(ws + 386304);                    // N*64*2 = 33,554,304 B
    float* c_buf = (float*)(ws + 386304 + (size_t)N_NODES * 64 * 2);  // N*64*4 B

    prep<<<512, 256, 0, stream>>>(emb, W_iou, U_iou, W_f, U_f,
                                  b_Wiou, b_Uiou, b_Wf, b_Uf, Wcat, bias, emb16);

    for (int l = DEPTH - 1; l >= 8; l--) {
        int n = 1 << l;
        level_pass<<<n / NPB, 256, 0, stream>>>(Wcat, bias, emb16, token_ids,
                                                H, c_buf, n - 1, n, l == DEPTH - 1);
    }
    tail_pass<<<1, 256, 0, stream>>>(Wcat, bias, emb16, token_ids, H, c_buf, out);
}

// Round 4
// 241.970 us; speedup vs baseline: 1.5330x; 1.1880x over previous
//
#include <hip/hip_runtime.h>

typedef __bf16 bf16;
typedef __bf16 bf16x8 __attribute__((ext_vector_type(8)));
typedef float f32x4 __attribute__((ext_vector_type(4)));

#define DEPTH   18
#define N_NODES ((1 << DEPTH) - 1)      // 262143
#define KDIM    192                     // E + 2H
#define RDIM    320                     // 3H + 2H
#define A_PAD   200                     // padded A-row stride (bf16 elems)
#define CC_PAD  68                      // Cc row stride (f32), 16B-aligned, 4-way-max banks
#define LOG2E   1.4426950408889634f

__device__ __forceinline__ float rcpf(float x) { return __builtin_amdgcn_rcpf(x); }
// pre-activations pre-scaled by log2e (folded into Wcat/bias)
__device__ __forceinline__ float sig2(float p)  { return rcpf(1.f + exp2f(-p)); }
__device__ __forceinline__ float tanhf_(float x){ return 2.f * rcpf(1.f + exp2f(-2.f * LOG2E * x)) - 1.f; }

// ---- one-time: Wcat[320][192]*log2e -> bf16, bias*log2e, emb -> bf16 ----
__global__ void prep(const float* __restrict__ emb,
                     const float* __restrict__ W_iou, const float* __restrict__ U_iou,
                     const float* __restrict__ W_f,   const float* __restrict__ U_f,
                     const float* __restrict__ b_Wiou, const float* __restrict__ b_Uiou,
                     const float* __restrict__ b_Wf,   const float* __restrict__ b_Uf,
                     bf16* __restrict__ Wcat, float* __restrict__ bias, bf16* __restrict__ emb16) {
    int t = blockIdx.x * blockDim.x + threadIdx.x;
    if (t < 2048 * 64) emb16[t] = (bf16)emb[t];
    if (t < RDIM * KDIM) {
        int r = t / KDIM, k = t % KDIM;
        float v;
        if (r < 192) v = (k < 64) ? W_iou[r * 64 + k] : U_iou[r * 128 + (k - 64)];
        else { int rr = r - 192; v = (k < 64) ? W_f[rr * 64 + k] : U_f[rr * 128 + (k - 64)]; }
        Wcat[t] = (bf16)(v * LOG2E);
    }
    if (t < RDIM)
        bias[t] = ((t < 192) ? (b_Wiou[t] + b_Uiou[t]) : (b_Wf[t - 192] + b_Uf[t - 192])) * LOG2E;
}

// ---- one-time: leaf tables. Leaf h,c depend only on token: h_cat=0 =>
// pre = x@W + b (K=64, gates i,o,u only), c = i*u, h = o*tanh(c). ----
__global__ __launch_bounds__(256) void prep_leaf(
        const bf16* __restrict__ Wcat, const float* __restrict__ bias,
        const bf16* __restrict__ emb16, bf16* __restrict__ leafH, float* __restrict__ leafC) {
    __shared__ __align__(16) bf16 A[64 * 72];
    const int tid = threadIdx.x, v0 = blockIdx.x * 64;
    for (int ch = tid; ch < 64 * 8; ch += 256) {
        int row = ch >> 3, k8 = (ch & 7) << 3;
        *(uint4*)&A[row * 72 + k8] = *(const uint4*)(emb16 + (v0 + row) * 64 + k8);
    }
    __syncthreads();
    const int wave = tid >> 6, lane = tid & 63;
    const int l15 = lane & 15, quad = lane >> 4;
    const int jw = wave * 16, jb = jw + quad * 4;

    f32x4 acc[4][3];
#pragma unroll
    for (int t = 0; t < 4; t++)
#pragma unroll
        for (int g = 0; g < 3; g++) acc[t][g] = (f32x4){0.f, 0.f, 0.f, 0.f};
#pragma unroll
    for (int kb = 0; kb < 2; kb++) {
        bf16x8 wfrag[3], nfrag[4];
#pragma unroll
        for (int g = 0; g < 3; g++)
            wfrag[g] = *(const bf16x8*)(Wcat + (g * 64 + jw + l15) * KDIM + kb * 32 + quad * 8);
#pragma unroll
        for (int t = 0; t < 4; t++)
            nfrag[t] = *(const bf16x8*)(&A[(t * 16 + l15) * 72 + kb * 32 + quad * 8]);
#pragma unroll
        for (int t = 0; t < 4; t++)
#pragma unroll
            for (int g = 0; g < 3; g++)
                acc[t][g] = __builtin_amdgcn_mfma_f32_16x16x32_bf16(wfrag[g], nfrag[t], acc[t][g], 0, 0, 0);
    }
    const float4 bI = *(const float4*)(bias + jb);
    const float4 bO = *(const float4*)(bias + 64 + jb);
    const float4 bU = *(const float4*)(bias + 128 + jb);
    const float* pbI = &bI.x; const float* pbO = &bO.x; const float* pbU = &bU.x;
#pragma unroll
    for (int t = 0; t < 4; t++) {
        int v = v0 + t * 16 + l15;
        float4 c4; float* pc4 = &c4.x;
        union { bf16 h[4]; uint2 u; } hp;
#pragma unroll
        for (int r = 0; r < 4; r++) {
            float i_g = sig2(acc[t][0][r] + pbI[r]);
            float o_g = sig2(acc[t][1][r] + pbO[r]);
            float u_g = tanhf_(sig2(acc[t][2][r] + pbU[r]));
            float c = i_g * u_g;
            pc4[r] = c;
            hp.h[r] = (bf16)(o_g * tanhf_(c));
        }
        *(float4*)(leafC + (size_t)v * 64 + jb) = c4;
        *(uint2*)(leafH + (size_t)v * 64 + jb) = hp.u;
    }
}

// ---- pair kernel: block computes 64 children (level lc) + their 32 parents
// (level lc-1). Child h,c stay in LDS (h -> parent A-tile, c -> Cc aliasing
// the dead child A-tile). Only parent h,c go to global. is16: grandchildren
// are leaves -> gather from leafH/leafC tables. ----
__global__ __launch_bounds__(256) void pair_pass(
        const bf16* __restrict__ Wcat, const float* __restrict__ bias,
        const bf16* __restrict__ emb16, const int* __restrict__ token_ids,
        const bf16* __restrict__ leafH, const float* __restrict__ leafC,
        bf16* __restrict__ H, float* __restrict__ c_buf,
        int sc /*child level start*/, int is16) {
    __shared__ __align__(16) bf16 A1[64 * A_PAD];   // child tile; Cc aliases after child MFMA
    __shared__ __align__(16) bf16 A2[32 * A_PAD];   // parent tile
    float* Cc = (float*)A1;                          // Cc[child][CC_PAD]
    const int tid = threadIdx.x;
    const int c0 = blockIdx.x * 64;                  // child offset in level
    const int p0 = c0 >> 1;
    const int sp = (sc - 1) >> 1;                    // parent level start

    // stage child x (64 rows x 8 chunks)
    for (int ch = tid; ch < 64 * 8; ch += 256) {
        int row = ch >> 3, k8 = (ch & 7) << 3;
        int tok = token_ids[sc + c0 + row];
        *(uint4*)&A1[row * A_PAD + k8] = *(const uint4*)(emb16 + tok * 64 + k8);
    }
    // stage child h_cat (grandchildren h)
    if (is16) {
        for (int ch = tid; ch < 64 * 16; ch += 256) {
            int row = ch >> 4, half = (ch >> 3) & 1, k8 = (ch & 7) << 3;
            int gnc = sc + c0 + row;
            int tok = token_ids[2 * gnc + 1 + half];
            *(uint4*)&A1[row * A_PAD + 64 + half * 64 + k8] = *(const uint4*)(leafH + (size_t)tok * 64 + k8);
        }
    } else {
        for (int ch = tid; ch < 64 * 16; ch += 256) {
            int row = ch >> 4, k8 = (ch & 15) << 3;
            int gnc = sc + c0 + row;
            *(uint4*)&A1[row * A_PAD + 64 + k8] = *(const uint4*)(H + (size_t)(2 * gnc + 1) * 64 + k8);
        }
    }
    // stage parent x into A2 (cols 0..63)
    for (int ch = tid; ch < 32 * 8; ch += 256) {
        int row = ch >> 3, k8 = (ch & 7) << 3;
        int tok = token_ids[sp + p0 + row];
        *(uint4*)&A2[row * A_PAD + k8] = *(const uint4*)(emb16 + tok * 64 + k8);
    }
    __syncthreads();

    const int wave = tid >> 6, lane = tid & 63;
    const int l15 = lane & 15, quad = lane >> 4;
    const int jw = wave * 16, jb = jw + quad * 4;

    // ---- child MFMA ----
    f32x4 acc[4][5];
#pragma unroll
    for (int t = 0; t < 4; t++)
#pragma unroll
        for (int g = 0; g < 5; g++) acc[t][g] = (f32x4){0.f, 0.f, 0.f, 0.f};
#pragma unroll
    for (int kb = 0; kb < 6; kb++) {
        bf16x8 wfrag[5], nfrag[4];
#pragma unroll
        for (int g = 0; g < 5; g++)
            wfrag[g] = *(const bf16x8*)(Wcat + (g * 64 + jw + l15) * KDIM + kb * 32 + quad * 8);
#pragma unroll
        for (int t = 0; t < 4; t++)
            nfrag[t] = *(const bf16x8*)(&A1[(t * 16 + l15) * A_PAD + kb * 32 + quad * 8]);
#pragma unroll
        for (int t = 0; t < 4; t++)
#pragma unroll
            for (int g = 0; g < 5; g++)
                acc[t][g] = __builtin_amdgcn_mfma_f32_16x16x32_bf16(wfrag[g], nfrag[t], acc[t][g], 0, 0, 0);
    }
    __syncthreads();   // all A1 reads done before Cc (alias) writes

    const float4 bI = *(const float4*)(bias + jb);
    const float4 bO = *(const float4*)(bias + 64 + jb);
    const float4 bU = *(const float4*)(bias + 128 + jb);
    const float4 bL = *(const float4*)(bias + 192 + jb);
    const float4 bR = *(const float4*)(bias + 256 + jb);
    const float* pbI = &bI.x; const float* pbO = &bO.x; const float* pbU = &bU.x;
    const float* pbL = &bL.x; const float* pbR = &bR.x;

    // ---- child epilogue: c -> Cc (LDS), h -> A2 h-slots (LDS) ----
#pragma unroll
    for (int t = 0; t < 4; t++) {
        const int ci = t * 16 + l15;
        const int gnc = sc + c0 + ci;
        float4 cl, cr;
        if (is16) {
            int tkl = token_ids[2 * gnc + 1], tkr = token_ids[2 * gnc + 2];
            cl = *(const float4*)(leafC + (size_t)tkl * 64 + jb);
            cr = *(const float4*)(leafC + (size_t)tkr * 64 + jb);
        } else {
            cl = *(const float4*)(c_buf + (size_t)(2 * gnc + 1) * 64 + jb);
            cr = *(const float4*)(c_buf + (size_t)(2 * gnc + 2) * 64 + jb);
        }
        const float* pcl = &cl.x; const float* pcr = &cr.x;
        float4 c4; float* pc4 = &c4.x;
        union { bf16 h[4]; uint2 u; } hp;
#pragma unroll
        for (int r = 0; r < 4; r++) {
            float i_g = sig2(acc[t][0][r] + pbI[r]);
            float o_g = sig2(acc[t][1][r] + pbO[r]);
            float u_g = tanhf_(sig2(acc[t][2][r] + pbU[r]));
            float fl  = sig2(acc[t][3][r] + pbL[r]);
            float fr  = sig2(acc[t][4][r] + pbR[r]);
            float c = i_g * u_g + fl * pcl[r] + fr * pcr[r];
            pc4[r] = c;
            hp.h[r] = (bf16)(o_g * tanhf_(c));
        }
        *(float4*)(Cc + ci * CC_PAD + jb) = c4;
        *(uint2*)(&A2[(ci >> 1) * A_PAD + 64 + (ci & 1) * 64 + jb]) = hp.u;
    }
    __syncthreads();   // A2 + Cc complete

    // ---- parent MFMA (32 nodes = 2 t-tiles) ----
    f32x4 pacc[2][5];
#pragma unroll
    for (int t = 0; t < 2; t++)
#pragma unroll
        for (int g = 0; g < 5; g++) pacc[t][g] = (f32x4){0.f, 0.f, 0.f, 0.f};
#pragma unroll
    for (int kb = 0; kb < 6; kb++) {
        bf16x8 wfrag[5], nfrag[2];
#pragma unroll
        for (int g = 0; g < 5; g++)
            wfrag[g] = *(const bf16x8*)(Wcat + (g * 64 + jw + l15) * KDIM + kb * 32 + quad * 8);
#pragma unroll
        for (int t = 0; t < 2; t++)
            nfrag[t] = *(const bf16x8*)(&A2[(t * 16 + l15) * A_PAD + kb * 32 + quad * 8]);
#pragma unroll
        for (int t = 0; t < 2; t++)
#pragma unroll
            for (int g = 0; g < 5; g++)
                pacc[t][g] = __builtin_amdgcn_mfma_f32_16x16x32_bf16(wfrag[g], nfrag[t], pacc[t][g], 0, 0, 0);
    }

    // ---- parent epilogue: h,c -> global ----
#pragma unroll
    for (int t = 0; t < 2; t++) {
        const int p = t * 16 + l15;
        const int gp = sp + p0 + p;
        float4 cl = *(const float4*)(Cc + (2 * p) * CC_PAD + jb);
        float4 cr = *(const float4*)(Cc + (2 * p + 1) * CC_PAD + jb);
        const float* pcl = &cl.x; const float* pcr = &cr.x;
        float4 c4; float* pc4 = &c4.x;
        union { bf16 h[4]; uint2 u; } hp;
#pragma unroll
        for (int r = 0; r < 4; r++) {
            float i_g = sig2(pacc[t][0][r] + pbI[r]);
            float o_g = sig2(pacc[t][1][r] + pbO[r]);
            float u_g = tanhf_(sig2(pacc[t][2][r] + pbU[r]));
            float fl  = sig2(pacc[t][3][r] + pbL[r]);
            float fr  = sig2(pacc[t][4][r] + pbR[r]);
            float c = i_g * u_g + fl * pcl[r] + fr * pcr[r];
            pc4[r] = c;
            hp.h[r] = (bf16)(o_g * tanhf_(c));
        }
        *(float4*)(c_buf + (size_t)gp * 64 + jb) = c4;
        *(uint2*)(H + (size_t)gp * 64 + jb) = hp.u;
    }
}

// ---- tail: levels 8..0 (511 nodes) in ONE block; level-8 children (level-9
// h/c) read from global (L2); h ping-pong in LDS below that; c via global L2
// (same-workgroup: __syncthreads suffices). ----
__global__ __launch_bounds__(256) void tail_pass(
        const bf16* __restrict__ Wcat, const float* __restrict__ bias,
        const bf16* __restrict__ emb16, const int* __restrict__ token_ids,
        const bf16* __restrict__ H, float* c_buf, float* out) {
    __shared__ __align__(16) bf16 buf0[128 * 136];   // pair p = [h(left)|h(right)] + pad
    __shared__ __align__(16) bf16 buf1[64 * 136];
    const int tid = threadIdx.x;
    const int wave = tid >> 6, lane = tid & 63;
    const int l15 = lane & 15, quad = lane >> 4;
    const int jw = wave * 16, jb = jw + quad * 4;
    const float4 bI = *(const float4*)(bias + jb);
    const float4 bO = *(const float4*)(bias + 64 + jb);
    const float4 bU = *(const float4*)(bias + 128 + jb);
    const float4 bL = *(const float4*)(bias + 192 + jb);
    const float4 bR = *(const float4*)(bias + 256 + jb);
    const float* pbI = &bI.x; const float* pbO = &bO.x; const float* pbU = &bU.x;
    const float* pbL = &bL.x; const float* pbR = &bR.x;

    bf16* prev = buf1;     // unused at l=8 (children come from global H)
    bf16* cur  = buf0;

    for (int l = 8; l >= 0; l--) {
        const int n = 1 << l, start = n - 1;
        for (int c0 = 0; c0 < n; c0 += 64) {
            f32x4 acc[4][5];
#pragma unroll
            for (int t = 0; t < 4; t++)
#pragma unroll
                for (int g = 0; g < 5; g++) acc[t][g] = (f32x4){0.f, 0.f, 0.f, 0.f};

            int toks[4], idxc[4];
#pragma unroll
            for (int t = 0; t < 4; t++) {
                int idx = c0 + t * 16 + l15;
                idxc[t] = (idx < n) ? idx : (n - 1);      // clamp (LDS/global reads)
                toks[t] = token_ids[start + idx];          // deeper-tree tokens OK (discarded)
            }
#pragma unroll
            for (int kb = 0; kb < 6; kb++) {
                bf16x8 wfrag[5], nfrag[4];
#pragma unroll
                for (int g = 0; g < 5; g++)
                    wfrag[g] = *(const bf16x8*)(Wcat + (g * 64 + jw + l15) * KDIM + kb * 32 + quad * 8);
#pragma unroll
                for (int t = 0; t < 4; t++) {
                    if (kb < 2)
                        nfrag[t] = *(const bf16x8*)(emb16 + toks[t] * 64 + kb * 32 + quad * 8);
                    else if (l == 8) {
                        int gn = start + idxc[t];
                        nfrag[t] = *(const bf16x8*)(H + (size_t)(2 * gn + 1) * 64 + (kb * 32 + quad * 8 - 64));
                    } else
                        nfrag[t] = *(const bf16x8*)(prev + idxc[t] * 136 + (kb * 32 + quad * 8 - 64));
                }
#pragma unroll
                for (int t = 0; t < 4; t++)
#pragma unroll
                    for (int g = 0; g < 5; g++)
                        acc[t][g] = __builtin_amdgcn_mfma_f32_16x16x32_bf16(wfrag[g], nfrag[t], acc[t][g], 0, 0, 0);
            }
#pragma unroll
            for (int t = 0; t < 4; t++) {
                const int idx = c0 + t * 16 + l15;
                if (idx >= n) continue;
                const int gn = start + idx;
                float4 cl = *(const float4*)(c_buf + (size_t)(2 * gn + 1) * 64 + jb);
                float4 cr = *(const float4*)(c_buf + (size_t)(2 * gn + 2) * 64 + jb);
                const float* pcl = &cl.x; const float* pcr = &cr.x;
                float4 c4, h4; float* pc4 = &c4.x; float* ph4 = &h4.x;
                union { bf16 h[4]; uint2 u; } hp;
#pragma unroll
                for (int r = 0; r < 4; r++) {
                    float i_g = sig2(acc[t][0][r] + pbI[r]);
                    float o_g = sig2(acc[t][1][r] + pbO[r]);
                    float u_g = tanhf_(sig2(acc[t][2][r] + pbU[r]));
                    float fl  = sig2(acc[t][3][r] + pbL[r]);
                    float fr  = sig2(acc[t][4][r] + pbR[r]);
                    float c = i_g * u_g + fl * pcl[r] + fr * pcr[r];
                    pc4[r] = c;
                    float h = o_g * tanhf_(c);
                    ph4[r] = h;
                    hp.h[r] = (bf16)h;
                }
                *(float4*)(c_buf + (size_t)gn * 64 + jb) = c4;
                if (l) {
                    *(uint2*)(cur + (idx >> 1) * 136 + (idx & 1) * 64 + jb) = hp.u;
                } else {
                    *(float4*)(out + jb) = h4;            // stack([h, c]): h
                    *(float4*)(out + 64 + jb) = c4;       // c
                }
            }
        }
        __syncthreads();      // same-CU global c_buf visibility: barrier suffices
        bf16* tmp = prev; prev = cur; cur = tmp;
    }
}

extern "C" void kernel_launch(void* const* d_in, const int* in_sizes, int n_in,
                              void* d_out, int out_size, void* d_ws, size_t ws_size,
                              hipStream_t stream) {
    const int*   token_ids = (const int*)d_in[0];
    const float* emb       = (const float*)d_in[1];
    const float* W_iou     = (const float*)d_in[2];
    const float* b_Wiou    = (const float*)d_in[3];
    const float* U_iou     = (const float*)d_in[4];
    const float* b_Uiou    = (const float*)d_in[5];
    const float* W_f       = (const float*)d_in[6];
    const float* b_Wf      = (const float*)d_in[7];
    const float* U_f       = (const float*)d_in[8];
    const float* b_Uf      = (const float*)d_in[9];
    float* out = (float*)d_out;

    char* ws = (char*)d_ws;
    bf16*  Wcat  = (bf16*)ws;                               // 122880 B
    float* bias  = (float*)(ws + 122880);                   // 1280 B -> 124160
    bf16*  emb16 = (bf16*)(ws + 124160);                    // 262144 B -> 386304
    bf16*  leafH = (bf16*)(ws + 386304);                    // 262144 B -> 648448
    float* leafC = (float*)(ws + 648448);                   // 524288 B -> 1172736
    bf16*  H     = (bf16*)(ws + 1172736);                   // 33554304 B -> 34727040
    float* c_buf = (float*)(ws + 34727040);                 // 67108608 B

    prep<<<512, 256, 0, stream>>>(emb, W_iou, U_iou, W_f, U_f,
                                  b_Wiou, b_Uiou, b_Wf, b_Uf, Wcat, bias, emb16);
    prep_leaf<<<32, 256, 0, stream>>>(Wcat, bias, emb16, leafH, leafC);

    // pairs: (children level start, is16): levels (16,15),(14,13),(12,11),(10,9)
    pair_pass<<<1024, 256, 0, stream>>>(Wcat, bias, emb16, token_ids, leafH, leafC,
                                        H, c_buf, 65535, 1);
    pair_pass<<<256, 256, 0, stream>>>(Wcat, bias, emb16, token_ids, leafH, leafC,
                                       H, c_buf, 16383, 0);
    pair_pass<<<64, 256, 0, stream>>>(Wcat, bias, emb16, token_ids, leafH, leafC,
                                      H, c_buf, 4095, 0);
    pair_pass<<<16, 256, 0, stream>>>(Wcat, bias, emb16, token_ids, leafH, leafC,
                                      H, c_buf, 1023, 0);
    tail_pass<<<1, 256, 0, stream>>>(Wcat, bias, emb16, token_ids, H, c_buf, out);
}

// Round 5
// 211.604 us; speedup vs baseline: 1.7529x; 1.1435x over previous
//
#include <hip/hip_runtime.h>

typedef __bf16 bf16;
typedef __bf16 bf16x8 __attribute__((ext_vector_type(8)));
typedef float f32x4 __attribute__((ext_vector_type(4)));

#define DEPTH   18
#define N_NODES ((1 << DEPTH) - 1)      // 262143
#define KDIM    192                     // E + 2H
#define RDIM    320                     // 3H + 2H
#define A_PAD   200                     // padded A-row stride (bf16 elems)
#define LOG2E   1.4426950408889634f

__device__ __forceinline__ float rcpf(float x) { return __builtin_amdgcn_rcpf(x); }
// pre-activations pre-scaled by log2e (folded into Wcat/bias)
__device__ __forceinline__ float sig2(float p)  { return rcpf(1.f + exp2f(-p)); }
__device__ __forceinline__ float tanhf_(float x){ return 2.f * rcpf(1.f + exp2f(-2.f * LOG2E * x)) - 1.f; }

// shared epilogue: acc[5] + biases + children c -> c4, h4
__device__ __forceinline__ void gates(const f32x4* acc,
        const float4& bI, const float4& bO, const float4& bU,
        const float4& bL, const float4& bR,
        const float4& cl, const float4& cr, float4& c4, float4& h4) {
    const float* pbI = &bI.x; const float* pbO = &bO.x; const float* pbU = &bU.x;
    const float* pbL = &bL.x; const float* pbR = &bR.x;
    const float* pcl = &cl.x; const float* pcr = &cr.x;
    float* pc4 = &c4.x; float* ph4 = &h4.x;
#pragma unroll
    for (int r = 0; r < 4; r++) {
        float i_g = sig2(acc[0][r] + pbI[r]);
        float o_g = sig2(acc[1][r] + pbO[r]);
        float u_g = tanhf_(sig2(acc[2][r] + pbU[r]));   // ref: tanh(sigmoid(pre_u))
        float fl  = sig2(acc[3][r] + pbL[r]);
        float fr  = sig2(acc[4][r] + pbR[r]);
        float c = i_g * u_g + fl * pcl[r] + fr * pcr[r];
        pc4[r] = c;
        ph4[r] = o_g * tanhf_(c);
    }
}

// ---- dispatch 1: blocks 0..511 elementwise pack (Wcat, bias, emb16);
// blocks 512..543 leaf tables (independent: convert own W/emb slices). ----
__global__ void prep_all(const float* __restrict__ emb,
                     const float* __restrict__ W_iou, const float* __restrict__ U_iou,
                     const float* __restrict__ W_f,   const float* __restrict__ U_f,
                     const float* __restrict__ b_Wiou, const float* __restrict__ b_Uiou,
                     const float* __restrict__ b_Wf,   const float* __restrict__ b_Uf,
                     bf16* __restrict__ Wcat, float* __restrict__ bias, bf16* __restrict__ emb16,
                     bf16* __restrict__ leafH, float* __restrict__ leafC) {
    __shared__ __align__(16) bf16 Wl[192 * 72];
    __shared__ __align__(16) bf16 Al[64 * 72];
    const int blk = blockIdx.x, tid = threadIdx.x;
    if (blk < 512) {
        int t = blk * 256 + tid;                 // t < 131072 == 2048*64
        emb16[t] = (bf16)emb[t];
        if (t < RDIM * KDIM) {
            int r = t / KDIM, k = t % KDIM;
            float v;
            if (r < 192) v = (k < 64) ? W_iou[r * 64 + k] : U_iou[r * 128 + (k - 64)];
            else { int rr = r - 192; v = (k < 64) ? W_f[rr * 64 + k] : U_f[rr * 128 + (k - 64)]; }
            Wcat[t] = (bf16)(v * LOG2E);
        }
        if (t < RDIM)
            bias[t] = ((t < 192) ? (b_Wiou[t] + b_Uiou[t]) : (b_Wf[t - 192] + b_Uf[t - 192])) * LOG2E;
        return;
    }
    // ---- leaf-table block: vocab slice [v0, v0+64) ----
    const int v0 = (blk - 512) * 64;
    for (int i = tid; i < 192 * 64; i += 256) {
        int r = i >> 6, k = i & 63;
        Wl[r * 72 + k] = (bf16)(W_iou[i] * LOG2E);
    }
    for (int i = tid; i < 64 * 64; i += 256) {
        int r = i >> 6, k = i & 63;
        Al[r * 72 + k] = (bf16)emb[(v0 << 6) + i];
    }
    __syncthreads();
    const int wave = tid >> 6, lane = tid & 63;
    const int l15 = lane & 15, quad = lane >> 4;
    const int jw = (wave & 3) * 16, jb = jw + quad * 4;

    f32x4 acc[4][3];
#pragma unroll
    for (int t = 0; t < 4; t++)
#pragma unroll
        for (int g = 0; g < 3; g++) acc[t][g] = (f32x4){0.f, 0.f, 0.f, 0.f};
#pragma unroll
    for (int kb = 0; kb < 2; kb++) {
        bf16x8 wfrag[3], nfrag[4];
#pragma unroll
        for (int g = 0; g < 3; g++)
            wfrag[g] = *(const bf16x8*)(&Wl[(g * 64 + jw + l15) * 72 + kb * 32 + quad * 8]);
#pragma unroll
        for (int t = 0; t < 4; t++)
            nfrag[t] = *(const bf16x8*)(&Al[(t * 16 + l15) * 72 + kb * 32 + quad * 8]);
#pragma unroll
        for (int t = 0; t < 4; t++)
#pragma unroll
            for (int g = 0; g < 3; g++)
                acc[t][g] = __builtin_amdgcn_mfma_f32_16x16x32_bf16(wfrag[g], nfrag[t], acc[t][g], 0, 0, 0);
    }
    float4 bW, bU_;
    bW = *(const float4*)(b_Wiou + jb);       bU_ = *(const float4*)(b_Uiou + jb);
    float4 bI = make_float4((bW.x + bU_.x) * LOG2E, (bW.y + bU_.y) * LOG2E, (bW.z + bU_.z) * LOG2E, (bW.w + bU_.w) * LOG2E);
    bW = *(const float4*)(b_Wiou + 64 + jb);  bU_ = *(const float4*)(b_Uiou + 64 + jb);
    float4 bO = make_float4((bW.x + bU_.x) * LOG2E, (bW.y + bU_.y) * LOG2E, (bW.z + bU_.z) * LOG2E, (bW.w + bU_.w) * LOG2E);
    bW = *(const float4*)(b_Wiou + 128 + jb); bU_ = *(const float4*)(b_Uiou + 128 + jb);
    float4 bU = make_float4((bW.x + bU_.x) * LOG2E, (bW.y + bU_.y) * LOG2E, (bW.z + bU_.z) * LOG2E, (bW.w + bU_.w) * LOG2E);
    const float* pbI = &bI.x; const float* pbO = &bO.x; const float* pbU = &bU.x;
#pragma unroll
    for (int t = 0; t < 4; t++) {
        int v = v0 + t * 16 + l15;
        float4 c4; float* pc4 = &c4.x;
        union { bf16 h[4]; uint2 u; } hp;
#pragma unroll
        for (int r = 0; r < 4; r++) {
            float i_g = sig2(acc[t][0][r] + pbI[r]);
            float o_g = sig2(acc[t][1][r] + pbO[r]);
            float u_g = tanhf_(sig2(acc[t][2][r] + pbU[r]));
            float c = i_g * u_g;
            pc4[r] = c;
            hp.h[r] = (bf16)(o_g * tanhf_(c));
        }
        *(float4*)(leafC + (size_t)v * 64 + jb) = c4;
        *(uint2*)(leafH + (size_t)v * 64 + jb) = hp.u;
    }
}

// ---- dispatch 2: levels (16,15). 64 children + 32 parents per block; child
// h,c stay in LDS; grandchildren (leaves) gathered from leafH/leafC. ----
__global__ __launch_bounds__(256) void pair_pass(
        const bf16* __restrict__ Wcat, const float* __restrict__ bias,
        const bf16* __restrict__ emb16, const int* __restrict__ token_ids,
        const bf16* __restrict__ leafH, const float* __restrict__ leafC,
        bf16* __restrict__ H, float* __restrict__ c_buf) {
    __shared__ __align__(16) bf16 A1[64 * A_PAD];   // child tile; Cc aliases after child MFMA
    __shared__ __align__(16) bf16 A2[32 * A_PAD];   // parent tile
    float* Cc = (float*)A1;                          // Cc[child][68]
    const int tid = threadIdx.x;
    const int c0 = blockIdx.x * 64;
    const int p0 = c0 >> 1;
    const int sc = 65535, sp = 32767;

    for (int ch = tid; ch < 64 * 8; ch += 256) {
        int row = ch >> 3, k8 = (ch & 7) << 3;
        int tok = token_ids[sc + c0 + row];
        *(uint4*)&A1[row * A_PAD + k8] = *(const uint4*)(emb16 + tok * 64 + k8);
    }
    for (int ch = tid; ch < 64 * 16; ch += 256) {
        int row = ch >> 4, half = (ch >> 3) & 1, k8 = (ch & 7) << 3;
        int gnc = sc + c0 + row;
        int tok = token_ids[2 * gnc + 1 + half];
        *(uint4*)&A1[row * A_PAD + 64 + half * 64 + k8] = *(const uint4*)(leafH + (size_t)tok * 64 + k8);
    }
    for (int ch = tid; ch < 32 * 8; ch += 256) {
        int row = ch >> 3, k8 = (ch & 7) << 3;
        int tok = token_ids[sp + p0 + row];
        *(uint4*)&A2[row * A_PAD + k8] = *(const uint4*)(emb16 + tok * 64 + k8);
    }
    __syncthreads();

    const int wave = tid >> 6, lane = tid & 63;
    const int l15 = lane & 15, quad = lane >> 4;
    const int jw = wave * 16, jb = jw + quad * 4;

    f32x4 acc[4][5];
#pragma unroll
    for (int t = 0; t < 4; t++)
#pragma unroll
        for (int g = 0; g < 5; g++) acc[t][g] = (f32x4){0.f, 0.f, 0.f, 0.f};
#pragma unroll
    for (int kb = 0; kb < 6; kb++) {
        bf16x8 wfrag[5], nfrag[4];
#pragma unroll
        for (int g = 0; g < 5; g++)
            wfrag[g] = *(const bf16x8*)(Wcat + (g * 64 + jw + l15) * KDIM + kb * 32 + quad * 8);
#pragma unroll
        for (int t = 0; t < 4; t++)
            nfrag[t] = *(const bf16x8*)(&A1[(t * 16 + l15) * A_PAD + kb * 32 + quad * 8]);
#pragma unroll
        for (int t = 0; t < 4; t++)
#pragma unroll
            for (int g = 0; g < 5; g++)
                acc[t][g] = __builtin_amdgcn_mfma_f32_16x16x32_bf16(wfrag[g], nfrag[t], acc[t][g], 0, 0, 0);
    }
    __syncthreads();   // all A1 reads done before Cc (alias) writes

    const float4 bI = *(const float4*)(bias + jb);
    const float4 bO = *(const float4*)(bias + 64 + jb);
    const float4 bU = *(const float4*)(bias + 128 + jb);
    const float4 bL = *(const float4*)(bias + 192 + jb);
    const float4 bR = *(const float4*)(bias + 256 + jb);

#pragma unroll
    for (int t = 0; t < 4; t++) {
        const int ci = t * 16 + l15;
        const int gnc = sc + c0 + ci;
        int tkl = token_ids[2 * gnc + 1], tkr = token_ids[2 * gnc + 2];
        float4 cl = *(const float4*)(leafC + (size_t)tkl * 64 + jb);
        float4 cr = *(const float4*)(leafC + (size_t)tkr * 64 + jb);
        float4 c4, h4;
        gates(acc[t], bI, bO, bU, bL, bR, cl, cr, c4, h4);
        union { bf16 h[4]; uint2 u; } hp;
        const float* ph4 = &h4.x;
#pragma unroll
        for (int r = 0; r < 4; r++) hp.h[r] = (bf16)ph4[r];
        *(float4*)(Cc + ci * 68 + jb) = c4;
        *(uint2*)(&A2[(ci >> 1) * A_PAD + 64 + (ci & 1) * 64 + jb]) = hp.u;
    }
    __syncthreads();

    f32x4 pacc[2][5];
#pragma unroll
    for (int t = 0; t < 2; t++)
#pragma unroll
        for (int g = 0; g < 5; g++) pacc[t][g] = (f32x4){0.f, 0.f, 0.f, 0.f};
#pragma unroll
    for (int kb = 0; kb < 6; kb++) {
        bf16x8 wfrag[5], nfrag[2];
#pragma unroll
        for (int g = 0; g < 5; g++)
            wfrag[g] = *(const bf16x8*)(Wcat + (g * 64 + jw + l15) * KDIM + kb * 32 + quad * 8);
#pragma unroll
        for (int t = 0; t < 2; t++)
            nfrag[t] = *(const bf16x8*)(&A2[(t * 16 + l15) * A_PAD + kb * 32 + quad * 8]);
#pragma unroll
        for (int t = 0; t < 2; t++)
#pragma unroll
            for (int g = 0; g < 5; g++)
                pacc[t][g] = __builtin_amdgcn_mfma_f32_16x16x32_bf16(wfrag[g], nfrag[t], pacc[t][g], 0, 0, 0);
    }
#pragma unroll
    for (int t = 0; t < 2; t++) {
        const int p = t * 16 + l15;
        const int gp = sp + p0 + p;
        float4 cl = *(const float4*)(Cc + (2 * p) * 68 + jb);
        float4 cr = *(const float4*)(Cc + (2 * p + 1) * 68 + jb);
        float4 c4, h4;
        gates(pacc[t], bI, bO, bU, bL, bR, cl, cr, c4, h4);
        union { bf16 h[4]; uint2 u; } hp;
        const float* ph4 = &h4.x;
#pragma unroll
        for (int r = 0; r < 4; r++) hp.h[r] = (bf16)ph4[r];
        *(float4*)(c_buf + (size_t)gp * 64 + jb) = c4;
        *(uint2*)(H + (size_t)gp * 64 + jb) = hp.u;
    }
}

// ---- dispatch 3: levels 14..9 in one kernel. 256 blocks x 512 thr (8 waves:
// wj = j-range, wt = tile split). W in registers; h ping-pong in LDS A-tiles;
// c via global L2 (same-block barrier visibility). Level 9 h,c -> global. ----
__global__ __launch_bounds__(512, 2) void mid_pass(
        const bf16* __restrict__ Wcat, const float* __restrict__ bias,
        const bf16* __restrict__ emb16, const int* __restrict__ token_ids,
        bf16* __restrict__ H, float* __restrict__ c_buf) {
    __shared__ __align__(16) bf16 A0[64 * A_PAD];
    __shared__ __align__(16) bf16 A1[32 * A_PAD];
    const int tid = threadIdx.x, blk = blockIdx.x;
    const int wave = tid >> 6, lane = tid & 63;
    const int l15 = lane & 15, quad = lane >> 4;
    const int wj = wave & 3, wt = wave >> 2;
    const int jw = wj * 16, jb = jw + quad * 4;

    // stage level-14 tile: x + children (level-15) h
    {
        int row = tid >> 3, k8 = (tid & 7) << 3;
        int tok = token_ids[16383 + blk * 64 + row];
        *(uint4*)&A0[row * A_PAD + k8] = *(const uint4*)(emb16 + tok * 64 + k8);
    }
    for (int ch = tid; ch < 1024; ch += 512) {
        int row = ch >> 4, k8 = (ch & 15) << 3;
        int gnc = 16383 + blk * 64 + row;
        *(uint4*)&A0[row * A_PAD + 64 + k8] = *(const uint4*)(H + (size_t)(2 * gnc + 1) * 64 + k8);
    }

    // loop-invariant W fragments -> registers (30 x bf16x8)
    bf16x8 Wf[5][6];
#pragma unroll
    for (int g = 0; g < 5; g++)
#pragma unroll
        for (int kb = 0; kb < 6; kb++)
            Wf[g][kb] = *(const bf16x8*)(Wcat + (g * 64 + jw + l15) * KDIM + kb * 32 + quad * 8);

    const float4 bI = *(const float4*)(bias + jb);
    const float4 bO = *(const float4*)(bias + 64 + jb);
    const float4 bU = *(const float4*)(bias + 128 + jb);
    const float4 bL = *(const float4*)(bias + 192 + jb);
    const float4 bR = *(const float4*)(bias + 256 + jb);
    __syncthreads();

    bf16* Acur = A0;
    bf16* Anx  = A1;
    for (int l = 14; l >= 9; l--) {
        const int m = 1 << (l - 8);          // 64,32,16,8,4,2
        const int s = (1 << l) - 1, o = blk * m;
        const int T = (m + 15) >> 4;
        for (int ti = wt; ti < T; ti += 2) {
            int idx0 = ti * 16 + l15;
            int idx = idx0 < m ? idx0 : m - 1;
            int gn = s + o + idx;
            float4 cl = *(const float4*)(c_buf + (size_t)(2 * gn + 1) * 64 + jb);
            float4 cr = *(const float4*)(c_buf + (size_t)(2 * gn + 2) * 64 + jb);
            f32x4 acc[5];
#pragma unroll
            for (int g = 0; g < 5; g++) acc[g] = (f32x4){0.f, 0.f, 0.f, 0.f};
#pragma unroll
            for (int kb = 0; kb < 6; kb++) {
                bf16x8 nf = *(const bf16x8*)(&Acur[idx * A_PAD + kb * 32 + quad * 8]);
#pragma unroll
                for (int g = 0; g < 5; g++)
                    acc[g] = __builtin_amdgcn_mfma_f32_16x16x32_bf16(Wf[g][kb], nf, acc[g], 0, 0, 0);
            }
            float4 c4, h4;
            gates(acc, bI, bO, bU, bL, bR, cl, cr, c4, h4);
            if (idx0 < m) {
                union { bf16 h[4]; uint2 u; } hp;
                const float* ph4 = &h4.x;
#pragma unroll
                for (int r = 0; r < 4; r++) hp.h[r] = (bf16)ph4[r];
                *(float4*)(c_buf + (size_t)gn * 64 + jb) = c4;
                if (l > 9)
                    *(uint2*)(&Anx[(idx >> 1) * A_PAD + 64 + (idx & 1) * 64 + jb]) = hp.u;
                else
                    *(uint2*)(H + (size_t)gn * 64 + jb) = hp.u;
            }
        }
        if (l > 9) {   // stage next level's x (h-slots filled by epilogue above)
            int mn = m >> 1, sn = (1 << (l - 1)) - 1, on = blk * mn;
            for (int ch = tid; ch < mn * 8; ch += 512) {
                int row = ch >> 3, k8 = (ch & 7) << 3;
                int tok = token_ids[sn + on + row];
                *(uint4*)&Anx[row * A_PAD + k8] = *(const uint4*)(emb16 + tok * 64 + k8);
            }
        }
        __syncthreads();
        bf16* tmp = Acur; Acur = Anx; Anx = tmp;
    }
}

// ---- dispatch 4: levels 8..0, ONE block x 512 thr (8 waves). W in registers;
// h,c via global L2 (same-block barrier visibility). ----
__global__ __launch_bounds__(512, 2) void tail_pass(
        const bf16* __restrict__ Wcat, const float* __restrict__ bias,
        const bf16* __restrict__ emb16, const int* __restrict__ token_ids,
        bf16* __restrict__ H, float* __restrict__ c_buf, float* __restrict__ out) {
    const int tid = threadIdx.x;
    const int wave = tid >> 6, lane = tid & 63;
    const int l15 = lane & 15, quad = lane >> 4;
    const int wj = wave & 3, wt = wave >> 2;
    const int jw = wj * 16, jb = jw + quad * 4;

    bf16x8 Wf[5][6];
#pragma unroll
    for (int g = 0; g < 5; g++)
#pragma unroll
        for (int kb = 0; kb < 6; kb++)
            Wf[g][kb] = *(const bf16x8*)(Wcat + (g * 64 + jw + l15) * KDIM + kb * 32 + quad * 8);

    const float4 bI = *(const float4*)(bias + jb);
    const float4 bO = *(const float4*)(bias + 64 + jb);
    const float4 bU = *(const float4*)(bias + 128 + jb);
    const float4 bL = *(const float4*)(bias + 192 + jb);
    const float4 bR = *(const float4*)(bias + 256 + jb);

    for (int l = 8; l >= 0; l--) {
        const int n = 1 << l, start = n - 1;
        const int T = (n + 15) >> 4;
        for (int ti = wt; ti < T; ti += 2) {
            int idx0 = ti * 16 + l15;
            int idx = idx0 < n ? idx0 : n - 1;
            int gn = start + idx;
            int tok = token_ids[gn];
            const bf16* hsrc = H + (size_t)(2 * gn + 1) * 64;   // children h, contiguous 256B
            float4 cl = *(const float4*)(c_buf + (size_t)(2 * gn + 1) * 64 + jb);
            float4 cr = *(const float4*)(c_buf + (size_t)(2 * gn + 2) * 64 + jb);
            bf16x8 nf[6];
            nf[0] = *(const bf16x8*)(emb16 + tok * 64 + quad * 8);
            nf[1] = *(const bf16x8*)(emb16 + tok * 64 + 32 + quad * 8);
#pragma unroll
            for (int kb = 2; kb < 6; kb++)
                nf[kb] = *(const bf16x8*)(hsrc + (kb - 2) * 32 + quad * 8);
            f32x4 acc[5];
#pragma unroll
            for (int g = 0; g < 5; g++) acc[g] = (f32x4){0.f, 0.f, 0.f, 0.f};
#pragma unroll
            for (int kb = 0; kb < 6; kb++)
#pragma unroll
                for (int g = 0; g < 5; g++)
                    acc[g] = __builtin_amdgcn_mfma_f32_16x16x32_bf16(Wf[g][kb], nf[kb], acc[g], 0, 0, 0);
            float4 c4, h4;
            gates(acc, bI, bO, bU, bL, bR, cl, cr, c4, h4);
            if (idx0 < n) {
                if (l > 0) {
                    union { bf16 h[4]; uint2 u; } hp;
                    const float* ph4 = &h4.x;
#pragma unroll
                    for (int r = 0; r < 4; r++) hp.h[r] = (bf16)ph4[r];
                    *(float4*)(c_buf + (size_t)gn * 64 + jb) = c4;
                    *(uint2*)(H + (size_t)gn * 64 + jb) = hp.u;
                } else {
                    *(float4*)(out + jb) = h4;        // stack([h, c]): h
                    *(float4*)(out + 64 + jb) = c4;   // c
                }
            }
        }
        __syncthreads();
    }
}

extern "C" void kernel_launch(void* const* d_in, const int* in_sizes, int n_in,
                              void* d_out, int out_size, void* d_ws, size_t ws_size,
                              hipStream_t stream) {
    const int*   token_ids = (const int*)d_in[0];
    const float* emb       = (const float*)d_in[1];
    const float* W_iou     = (const float*)d_in[2];
    const float* b_Wiou    = (const float*)d_in[3];
    const float* U_iou     = (const float*)d_in[4];
    const float* b_Uiou    = (const float*)d_in[5];
    const float* W_f       = (const float*)d_in[6];
    const float* b_Wf      = (const float*)d_in[7];
    const float* U_f       = (const float*)d_in[8];
    const float* b_Uf      = (const float*)d_in[9];
    float* out = (float*)d_out;

    char* ws = (char*)d_ws;
    bf16*  Wcat  = (bf16*)ws;                               // 122880 B
    float* bias  = (float*)(ws + 122880);                   // 1280 B -> 124160
    bf16*  emb16 = (bf16*)(ws + 124160);                    // 262144 B -> 386304
    bf16*  leafH = (bf16*)(ws + 386304);                    // 262144 B -> 648448
    float* leafC = (float*)(ws + 648448);                   // 524288 B -> 1172736
    bf16*  H     = (bf16*)(ws + 1172736);                   // 33554304 B -> 34727040
    float* c_buf = (float*)(ws + 34727040);                 // 67108608 B

    prep_all<<<544, 256, 0, stream>>>(emb, W_iou, U_iou, W_f, U_f,
                                      b_Wiou, b_Uiou, b_Wf, b_Uf,
                                      Wcat, bias, emb16, leafH, leafC);
    pair_pass<<<1024, 256, 0, stream>>>(Wcat, bias, emb16, token_ids, leafH, leafC, H, c_buf);
    mid_pass<<<256, 512, 0, stream>>>(Wcat, bias, emb16, token_ids, H, c_buf);
    tail_pass<<<1, 512, 0, stream>>>(Wcat, bias, emb16, token_ids, H, c_buf, out);
}